// Round 12
// baseline (870.293 us; speedup 1.0000x reference)
//
#include <hip/hip_runtime.h>
#include <math.h>

#define L_SEQ 2048
#define DMOD  1024
#define DIN   2048
#define NBATCH 2
#define NTOK  (NBATCH * L_SEQ)   // 4096 tokens
#define NST   16
#define RRANK 64
#define LOG2E 1.44269504088896f

#define GCHUNK 128                // chunks along L
#define CLEN   (L_SEQ / GCHUNK)   // 16 steps per chunk
#define SCHUNK 8                  // software-pipeline stage depth
#define NSTAGE (CLEN / SCHUNK)    // 2 stages per chunk

#define G4_KS   4                 // GEMM4 split-K factor
#define G4_KC   (2048 / G4_KS)    // 512 k per slice
#define G2_KS   16                // GEMM2 split-K factor
#define G2_KC   (2048 / G2_KS)    // 128 k per slice

typedef __attribute__((ext_vector_type(8))) short  short8;   // 8 bf16
typedef __attribute__((ext_vector_type(4))) float  f32x4;

__device__ __forceinline__ ushort f2bf(float f) {
    unsigned u = __float_as_uint(f);
    u += 0x7fffu + ((u >> 16) & 1u);
    return (ushort)(u >> 16);
}
__device__ __forceinline__ float bf2f(ushort u) {
    return __uint_as_float(((unsigned)u) << 16);
}
__device__ __forceinline__ float fexp2(float x) {
    return __builtin_amdgcn_exp2f(x);
}

// async global->LDS DMA, 16 B per lane; lds dest = wave-uniform base + lane*16
__device__ __forceinline__ void gload16(const ushort* g, ushort* l) {
    __builtin_amdgcn_global_load_lds(
        (const __attribute__((address_space(1))) unsigned int*)g,
        (__attribute__((address_space(3))) unsigned int*)l,
        16, 0, 0);
}

// ---------------------------------------------------------------------------
// Device helpers: flat cast (2048 elems/block) and 32x32 transpose-cast tile.
// ---------------------------------------------------------------------------
__device__ __forceinline__ void cast_body(
    const float* __restrict__ src, ushort* __restrict__ dst, int bid, int tid)
{
    int i = (bid * 256 + tid) * 8;
    float4 a = *(const float4*)(src + i);
    float4 b = *(const float4*)(src + i + 4);
    ushort4 o0 = make_ushort4(f2bf(a.x), f2bf(a.y), f2bf(a.z), f2bf(a.w));
    ushort4 o1 = make_ushort4(f2bf(b.x), f2bf(b.y), f2bf(b.z), f2bf(b.w));
    *(ushort4*)(dst + i)     = o0;
    *(ushort4*)(dst + i + 4) = o1;
}

__device__ __forceinline__ void tcast_body(
    const float* __restrict__ src, ushort* __restrict__ dst,
    int R, int C, int bx, int by, int tid)
{
    __shared__ float t[32][33];
    int tx = tid & 31;
    int ty = tid >> 5;          // 0..7
    int c0 = bx * 32;
    int r0 = by * 32;
    #pragma unroll
    for (int i = 0; i < 4; ++i)
        t[ty + i * 8][tx] = src[(size_t)(r0 + ty + i * 8) * C + c0 + tx];
    __syncthreads();
    #pragma unroll
    for (int i = 0; i < 4; ++i)
        dst[(size_t)(c0 + ty + i * 8) * R + r0 + tx] = f2bf(t[tx][ty + i * 8]);
}

// ---------------------------------------------------------------------------
// Fused prep: x cast + ALL weight transpose-casts in one launch.
// ---------------------------------------------------------------------------
__global__ __launch_bounds__(256) void prep_k(
    const float* __restrict__ x, const float* __restrict__ W_in,
    const float* __restrict__ W_dt, const float* __restrict__ W_x,
    const float* __restrict__ W_out,
    ushort* __restrict__ xb, ushort* __restrict__ Wib,
    ushort* __restrict__ Wdtb, ushort* __restrict__ Wxb,
    ushort* __restrict__ Wob)
{
    int bid = blockIdx.x, tid = threadIdx.x;
    if (bid < 2048) {
        cast_body(x, xb, bid, tid);
    } else if (bid < 6144) {
        int t = bid - 2048;                 // W_in: R=1024, C=4096
        tcast_body(W_in, Wib, 1024, 4096, t & 127, t >> 7, tid);
    } else if (bid < 6272) {
        int t = bid - 6144;                 // W_dt: R=64, C=2048
        tcast_body(W_dt, Wdtb, 64, 2048, t & 63, t >> 6, tid);
    } else if (bid < 6464) {
        int t = bid - 6272;                 // W_x: R=2048, C=96 -> [96][2048]
        tcast_body(W_x, Wxb, 2048, 96, t % 3, t / 3, tid);
    } else {
        int t = bid - 6464;                 // W_out: R=2048, C=1024
        tcast_body(W_out, Wob, 2048, 1024, t & 31, t >> 5, tid);
    }
}

// ---------------------------------------------------------------------------
// 256x256-tile 8-wave bf16 MFMA GEMM — r12: RING-2 LDS (64 KB) so TWO blocks
// co-reside per CU (TLP route).  Keeps r10's register read-ahead; accepts a
// full vmcnt(0) drain once per half-tile — the co-resident block's MFMA
// covers the drain (m114 implicit wave-level overlap).
// Slot safety: stage of unit(h+1) targets slot (h+1)&1, whose last readers
// (aHi(h-1) read-ahead in phase A(h-1)) were lgkm-confirmed >=2 barriers
// earlier.  Read-ahead of slot h+1 only after B(h)'s vmcnt(0)+barrier.
// NH even at all call sites (32, 16).  Split-K via blockIdx.z; column-split
// C2/nsplit as before.  __launch_bounds__(512,4): 4 waves/SIMD = 2 blk/CU.
// ---------------------------------------------------------------------------
__global__ __launch_bounds__(512, 4) void gemm8p(
    const ushort* __restrict__ A,    // [M][K] bf16
    const ushort* __restrict__ Bt,   // [N][K] bf16
    ushort* __restrict__ C,          // bf16, leading dim ldc
    int K, int kslice, int ldc, size_t zstride,
    ushort* __restrict__ C2, int nsplit)
{
    // [2 slots][A 8192 | B 8192] ushorts = 64 KB  -> 2 blocks/CU
    __shared__ ushort lds[32768];

    const int tid  = threadIdx.x;
    const int wave = tid >> 6;
    const int lane = tid & 63;
    const int wr   = wave >> 2;      // 0..1: wave-row (128 rows each)
    const int wc   = wave & 3;       // 0..3: wave-col (64 cols each)

    // XCD-chunked bijective swizzle (nwg % 8 == 0 for all call sites)
    const int gx = gridDim.x;
    int flat = blockIdx.y * gx + blockIdx.x;
    const int cpx = (gx * gridDim.y) >> 3;
    flat = (flat & 7) * cpx + (flat >> 3);
    const int bx = flat % gx;
    const int by = flat / gx;
    const int m0 = by * 256;
    const int n0 = bx * 256;
    const int kbeg = blockIdx.z * kslice;
    const int NH   = kslice >> 5;    // half-tiles of 32 k (even: 32 or 16)

    // --- staging source pointers (pre-swizzled global granule) ---
    const int rr  = tid >> 2;
    const int gsw = ((tid & 3) ^ ((tid >> 3) & 3)) * 8;
    const ushort* a0 = A  + (size_t)(m0 + rr)        * K + kbeg + gsw;
    const ushort* a1 = A  + (size_t)(m0 + 128 + rr)  * K + kbeg + gsw;
    const ushort* b0p = Bt + (size_t)(n0 + rr)       * K + kbeg + gsw;
    const ushort* b1p = Bt + (size_t)(n0 + 128 + rr) * K + kbeg + gsw;

    // stage one op-unit (A or B) of half-tile h_ into slot h_&1
    #define STAGE_H(op_, h_) do {                                              \
        const int ko_ = (h_) * 32;                                             \
        ushort* l_ = lds + ((h_) & 1) * 16384 + (op_) * 8192 + wave * 512;     \
        if ((op_) == 0) { gload16(a0 + ko_, l_);  gload16(a1 + ko_, l_ + 4096); }\
        else            { gload16(b0p + ko_, l_); gload16(b1p + ko_, l_ + 4096); }\
    } while (0)

    // --- fragment read offsets (same verified involution as store side) ---
    const int lr  = lane & 15;
    const int swr = ((lane >> 4) ^ ((lr >> 1) & 3)) * 8;

    #define LDAH(i_, h_) (*(const short8*)&lds[((h_) & 1) * 16384              \
        + (wr * 128 + (i_) * 16 + lr) * 32 + swr])
    #define LDBH(j_, h_) (*(const short8*)&lds[((h_) & 1) * 16384 + 8192       \
        + (wc * 64 + (j_) * 16 + lr) * 32 + swr])

    #define MFMA16(as_, bs_, off_) do {                                        \
        __builtin_amdgcn_s_setprio(1);                                         \
        _Pragma("unroll")                                                      \
        for (int i = 0; i < 4; ++i)                                            \
            _Pragma("unroll")                                                  \
            for (int j = 0; j < 4; ++j)                                        \
                acc[(off_) + i][j] = __builtin_amdgcn_mfma_f32_16x16x32_bf16(  \
                    as_[i], bs_[j], acc[(off_) + i][j], 0, 0, 0);              \
        __builtin_amdgcn_s_setprio(0);                                         \
    } while (0)

    f32x4 acc[8][4];
    #pragma unroll
    for (int i = 0; i < 8; ++i)
        #pragma unroll
        for (int j = 0; j < 4; ++j)
            acc[i][j] = (f32x4){0.f, 0.f, 0.f, 0.f};

    // prologue: stage half-tile 0 (4 loads), drain, pre-read its fragments
    STAGE_H(0, 0); STAGE_H(1, 0);
    asm volatile("s_waitcnt vmcnt(0)" ::: "memory");
    __builtin_amdgcn_s_barrier();

    short8 aLo[4], aHi[4], bE[4], bO[4];
    #pragma unroll
    for (int i = 0; i < 4; ++i) aLo[i] = LDAH(i, 0);
    #pragma unroll
    for (int j = 0; j < 4; ++j) bE[j]  = LDBH(j, 0);

    for (int hp = 0; hp < NH / 2; ++hp) {
        const int h0 = 2 * hp, h1 = 2 * hp + 1;

        // ---- A(h0): MFMA(aLo,bE); stage A(h1); read-ahead aHi(h0) ---------
        STAGE_H(0, h1);
        __builtin_amdgcn_s_barrier();
        #pragma unroll
        for (int i = 0; i < 4; ++i) aHi[i] = LDAH(4 + i, h0);
        asm volatile("s_waitcnt lgkmcnt(4)" ::: "memory");
        __builtin_amdgcn_sched_barrier(0);
        MFMA16(aLo, bE, 0);
        __builtin_amdgcn_s_barrier();

        // ---- B(h0): MFMA(aHi,bE); stage B(h1); drain; read-ahead h1 -------
        STAGE_H(1, h1);
        asm volatile("s_waitcnt vmcnt(0)" ::: "memory");
        __builtin_amdgcn_s_barrier();
        #pragma unroll
        for (int i = 0; i < 4; ++i) aLo[i] = LDAH(i, h1);
        #pragma unroll
        for (int j = 0; j < 4; ++j) bO[j]  = LDBH(j, h1);
        asm volatile("s_waitcnt lgkmcnt(8)" ::: "memory");
        __builtin_amdgcn_sched_barrier(0);
        MFMA16(aHi, bE, 4);
        __builtin_amdgcn_s_barrier();

        // ---- A(h1): MFMA(aLo,bO); stage A(h1+1); read-ahead aHi(h1) -------
        if (h1 + 1 < NH) STAGE_H(0, h1 + 1);
        __builtin_amdgcn_s_barrier();
        #pragma unroll
        for (int i = 0; i < 4; ++i) aHi[i] = LDAH(4 + i, h1);
        asm volatile("s_waitcnt lgkmcnt(4)" ::: "memory");
        __builtin_amdgcn_sched_barrier(0);
        MFMA16(aLo, bO, 0);
        __builtin_amdgcn_s_barrier();

        // ---- B(h1): MFMA(aHi,bO); stage B(h1+1); drain; read-ahead --------
        if (h1 + 1 < NH) STAGE_H(1, h1 + 1);
        asm volatile("s_waitcnt vmcnt(0)" ::: "memory");
        __builtin_amdgcn_s_barrier();
        if (h1 + 1 < NH) {
            #pragma unroll
            for (int i = 0; i < 4; ++i) aLo[i] = LDAH(i, h1 + 1);
            #pragma unroll
            for (int j = 0; j < 4; ++j) bE[j]  = LDBH(j, h1 + 1);
            asm volatile("s_waitcnt lgkmcnt(8)" ::: "memory");
        } else {
            asm volatile("s_waitcnt lgkmcnt(0)" ::: "memory");
        }
        __builtin_amdgcn_sched_barrier(0);
        MFMA16(aHi, bO, 4);
        __builtin_amdgcn_s_barrier();
    }
    #undef STAGE_H
    #undef LDAH
    #undef LDBH
    #undef MFMA16

    // C/D layout: col = lane&15, row = (lane>>4)*4 + reg  (verified mapping)
    ushort* Cp = C + (size_t)blockIdx.z * zstride;
    int ncol = n0;
    if (C2 != nullptr && n0 >= nsplit) { Cp = C2; ncol = n0 - nsplit; }
    const int rb = m0 + wr * 128 + ((lane >> 4) << 2);
    const int cb = ncol + wc * 64 + lr;
    #pragma unroll
    for (int i = 0; i < 8; ++i)
        #pragma unroll
        for (int j = 0; j < 4; ++j)
            #pragma unroll
            for (int r = 0; r < 4; ++r)
                Cp[(size_t)(rb + i * 16 + r) * ldc + cb + j * 16] =
                    f2bf(acc[i][j][r]);
}

// ---------------------------------------------------------------------------
// bf16 MFMA GEMM, BK=32 + XOR-swizzled LDS. Kept for GEMM3 (K=64).
// EPI=1: softplus(acc + bias[col]) via hw exp2/log; bias hoisted.
// OBF=1 -> bf16 output (dlt stored as bf16).
// ---------------------------------------------------------------------------
template<int EPI, int OBF>
__global__ __launch_bounds__(256) void gemm_mfma(
    const ushort* __restrict__ A,   // [M][K] bf16
    const ushort* __restrict__ Bt,  // [N][K] bf16
    void* __restrict__ Cv,          // fp32 or bf16, leading dim ldc
    int M, int N, int K, int ldc, const float* __restrict__ bias)
{
    __shared__ ushort As[128 * 32];   // 8 KB
    __shared__ ushort Bs[128 * 32];

    const int tid  = threadIdx.x;
    const int wave = tid >> 6;
    const int lane = tid & 63;
    const int wm   = (wave & 1) * 64;
    const int wn   = (wave >> 1) * 64;
    const int m0   = blockIdx.y * 128;
    const int n0   = blockIdx.x * 128;

    const int srow = lane >> 2;                       // 0..15
    const int sg   = (lane & 3) ^ ((srow >> 1) & 3);  // swizzled src granule
    const ushort* gA0 = A  + (size_t)(m0 + wave * 32 + srow)      * K + sg * 8;
    const ushort* gA1 = A  + (size_t)(m0 + wave * 32 + 16 + srow) * K + sg * 8;
    const ushort* gB0 = Bt + (size_t)(n0 + wave * 32 + srow)      * K + sg * 8;
    const ushort* gB1 = Bt + (size_t)(n0 + wave * 32 + 16 + srow) * K + sg * 8;
    ushort* lA0 = As + (wave * 32)      * 32;
    ushort* lA1 = As + (wave * 32 + 16) * 32;
    ushort* lB0 = Bs + (wave * 32)      * 32;
    ushort* lB1 = Bs + (wave * 32 + 16) * 32;

    const int lrow = lane & 15;
    const int swr  = ((lane >> 4) ^ ((lrow >> 1) & 3)) * 8;

    f32x4 acc[4][4];
    #pragma unroll
    for (int i = 0; i < 4; ++i)
        #pragma unroll
        for (int j = 0; j < 4; ++j)
            acc[i][j] = (f32x4){0.f, 0.f, 0.f, 0.f};

    for (int k0 = 0; k0 < K; k0 += 32) {
        __syncthreads();
        gload16(gA0 + k0, lA0);
        gload16(gA1 + k0, lA1);
        gload16(gB0 + k0, lB0);
        gload16(gB1 + k0, lB1);
        __syncthreads();

        short8 af[4], bfr[4];
        #pragma unroll
        for (int i = 0; i < 4; ++i) {
            af[i]  = *(const short8*)&As[(wm + i * 16 + lrow) * 32 + swr];
            bfr[i] = *(const short8*)&Bs[(wn + i * 16 + lrow) * 32 + swr];
        }
        #pragma unroll
        for (int i = 0; i < 4; ++i)
            #pragma unroll
            for (int j = 0; j < 4; ++j)
                acc[i][j] = __builtin_amdgcn_mfma_f32_16x16x32_bf16(
                    af[i], bfr[j], acc[i][j], 0, 0, 0);
    }

    // C/D layout: col = lane&15, row = (lane>>4)*4 + reg
    const int rb = m0 + wm + ((lane >> 4) << 2);
    const int cb = n0 + wn + lrow;

    float bias4[4];
    if (EPI == 1) {
        #pragma unroll
        for (int j = 0; j < 4; ++j) bias4[j] = bias[cb + j * 16];
    }

    #pragma unroll
    for (int i = 0; i < 4; ++i)
        #pragma unroll
        for (int j = 0; j < 4; ++j)
            #pragma unroll
            for (int r = 0; r < 4; ++r) {
                float v = acc[i][j][r];
                int col = cb + j * 16;
                if (EPI == 1) {
                    v += bias4[j];
                    if (v <= 20.f) {
                        float t = fexp2(v * LOG2E);
                        v = __builtin_amdgcn_logf(1.f + t) * (1.f / LOG2E);
                    }
                }
                size_t off = (size_t)(rb + i * 16 + r) * ldc + col;
                if (OBF) ((ushort*)Cv)[off] = f2bf(v);
                else     ((float*)Cv)[off]  = v;
            }
}

// ---------------------------------------------------------------------------
// GEMM2 MFMA split-K: part[ks] (bf16) = ub @ Wxb^T over 128-k slice.
// ---------------------------------------------------------------------------
__global__ __launch_bounds__(256) void gemm2_mfma(
    const ushort* __restrict__ A,   // [4096][2048] bf16 = ub
    const ushort* __restrict__ Bt,  // [96][2048] bf16 = Wxb
    ushort* __restrict__ part)      // [16][4096][96] bf16
{
    __shared__ ushort As[128 * 32];
    __shared__ ushort Bs[128 * 32];

    const int K = 2048;
    const int tid  = threadIdx.x;
    const int wave = tid >> 6;
    const int lane = tid & 63;
    const int wm   = (wave & 1) * 64;
    const int wn   = (wave >> 1) * 64;
    const int m0   = blockIdx.x * 128;
    const int ks   = blockIdx.z;

    const int srow = lane >> 2;
    const int sg   = (lane & 3) ^ ((srow >> 1) & 3);
    int rB0 = wave * 32 + srow;      if (rB0 > 95) rB0 = 95;
    int rB1 = wave * 32 + 16 + srow; if (rB1 > 95) rB1 = 95;
    const ushort* gA0 = A  + (size_t)(m0 + wave * 32 + srow)      * K + sg * 8;
    const ushort* gA1 = A  + (size_t)(m0 + wave * 32 + 16 + srow) * K + sg * 8;
    const ushort* gB0 = Bt + (size_t)rB0 * K + sg * 8;
    const ushort* gB1 = Bt + (size_t)rB1 * K + sg * 8;
    ushort* lA0 = As + (wave * 32)      * 32;
    ushort* lA1 = As + (wave * 32 + 16) * 32;
    ushort* lB0 = Bs + (wave * 32)      * 32;
    ushort* lB1 = Bs + (wave * 32 + 16) * 32;

    const int lrow = lane & 15;
    const int swr  = ((lane >> 4) ^ ((lrow >> 1) & 3)) * 8;

    f32x4 acc[4][4];
    #pragma unroll
    for (int i = 0; i < 4; ++i)
        #pragma unroll
        for (int j = 0; j < 4; ++j)
            acc[i][j] = (f32x4){0.f, 0.f, 0.f, 0.f};

    const int kbeg = ks * G2_KC, kend = kbeg + G2_KC;
    for (int k0 = kbeg; k0 < kend; k0 += 32) {
        __syncthreads();
        gload16(gA0 + k0, lA0);
        gload16(gA1 + k0, lA1);
        gload16(gB0 + k0, lB0);
        gload16(gB1 + k0, lB1);
        __syncthreads();

        short8 af[4], bfr[4];
        #pragma unroll
        for (int i = 0; i < 4; ++i) {
            af[i]  = *(const short8*)&As[(wm + i * 16 + lrow) * 32 + swr];
            bfr[i] = *(const short8*)&Bs[(wn + i * 16 + lrow) * 32 + swr];
        }
        #pragma unroll
        for (int i = 0; i < 4; ++i)
            #pragma unroll
            for (int j = 0; j < 4; ++j)
                acc[i][j] = __builtin_amdgcn_mfma_f32_16x16x32_bf16(
                    af[i], bfr[j], acc[i][j], 0, 0, 0);
    }

    ushort* po = part + (size_t)ks * NTOK * 96;
    const int rb = m0 + wm + ((lane >> 4) << 2);
    const int cb = wn + lrow;
    #pragma unroll
    for (int i = 0; i < 4; ++i)
        #pragma unroll
        for (int j = 0; j < 4; ++j) {
            int col = cb + j * 16;
            if (col < 96) {
                #pragma unroll
                for (int r = 0; r < 4; ++r)
                    po[(size_t)(rb + i * 16 + r) * 96 + col] = f2bf(acc[i][j][r]);
            }
        }
}

// ---------------------------------------------------------------------------
// GEMM2 reduce (16 bf16 slices) + fused dt bf16 cast (cols 0:64 -> dtb).
// ---------------------------------------------------------------------------
__global__ __launch_bounds__(256) void gemm2_reduce_dt(
    const ushort* __restrict__ part, float* __restrict__ dbc,
    ushort* __restrict__ dtb)
{
    int i = (blockIdx.x * 256 + threadIdx.x) * 4;
    float4 s = {0.f, 0.f, 0.f, 0.f};
    #pragma unroll
    for (int ks = 0; ks < G2_KS; ++ks) {
        ushort4 v = *(const ushort4*)(part + (size_t)ks * NTOK * 96 + i);
        s.x += bf2f(v.x); s.y += bf2f(v.y); s.z += bf2f(v.z); s.w += bf2f(v.w);
    }
    *(float4*)(dbc + i) = s;
    int col = i % 96;
    if (col < RRANK) {
        int row = i / 96;
        ushort* q = dtb + (size_t)row * RRANK + col;
        q[0] = f2bf(s.x); q[1] = f2bf(s.y); q[2] = f2bf(s.z); q[3] = f2bf(s.w);
    }
}

// ---------------------------------------------------------------------------
// Causal depthwise conv (K=4) + SiLU.  Reads COMPACT u buffer [4096][2048].
// ---------------------------------------------------------------------------
__global__ __launch_bounds__(256) void conv_silu_k(
    const ushort* __restrict__ up, const float* __restrict__ w_conv,
    const float* __restrict__ b_conv, ushort* __restrict__ ub)
{
    const int token = blockIdx.x;          // 0..4095
    const int d     = threadIdx.x * 8;     // 0..2040
    const int t     = token & (L_SEQ - 1);

    float4 w[8];
    const float4* pw = (const float4*)(w_conv + (size_t)d * 4);
    #pragma unroll
    for (int i = 0; i < 8; ++i) w[i] = pw[i];

    float acc[8];
    {
        float4 bc0 = *(const float4*)(b_conv + d);
        float4 bc1 = *(const float4*)(b_conv + d + 4);
        acc[0] = bc0.x; acc[1] = bc0.y; acc[2] = bc0.z; acc[3] = bc0.w;
        acc[4] = bc1.x; acc[5] = bc1.y; acc[6] = bc1.z; acc[7] = bc1.w;
    }

    #pragma unroll
    for (int k = 0; k < 4; ++k) {
        int tt = t - 3 + k;
        if (tt >= 0) {
            short8 v = *(const short8*)(up + (size_t)(token - 3 + k) * 2048 + d);
            #pragma unroll
            for (int i = 0; i < 8; ++i)
                acc[i] += bf2f((ushort)v[i]) * (&w[i].x)[k];
        }
    }

    short8 o;
    #pragma unroll
    for (int i = 0; i < 8; ++i) {
        float s = acc[i] / (1.f + __expf(-acc[i]));
        o[i] = (short)f2bf(s);
    }
    *(short8*)(ub + (size_t)token * DIN + d) = o;
}

// ---------------------------------------------------------------------------
// Scan pass 1: 4-wave blocks, WAVE-PRIVATE LDS (no cross-wave sharing, NO
// __syncthreads).  dlt BF16.  Grid: NBATCH * (DIN/256) * GCHUNK = 2048.
// ---------------------------------------------------------------------------
__global__ __launch_bounds__(256) void scan_part1(
    const ushort* __restrict__ dlt,    // [4096][2048] bf16
    const ushort* __restrict__ ub,     // [4096][2048] bf16
    const float* __restrict__ dbc,
    const float* __restrict__ A_log,
    float* __restrict__ c_out,         // [2][2048][GCHUNK][16]
    float* __restrict__ dsum_out)      // [2][2048][GCHUNK]
{
    int chunk = blockIdx.x & (GCHUNK - 1);
    int dg    = (blockIdx.x >> 7) & 7;
    int b     = blockIdx.x >> 10;
    int wave  = threadIdx.x >> 6;
    int lane  = threadIdx.x & 63;
    int d     = dg * 256 + wave * 64 + lane;

    __shared__ float sB[4][SCHUNK][16];   // per-wave private slice

    float Al[NST];
    const float4* pA = (const float4*)(A_log + (size_t)d * NST);
    #pragma unroll
    for (int q = 0; q < 4; ++q) {
        float4 a = pA[q];
        Al[q*4+0] = -__expf(a.x) * LOG2E;
        Al[q*4+1] = -__expf(a.y) * LOG2E;
        Al[q*4+2] = -__expf(a.z) * LOG2E;
        Al[q*4+3] = -__expf(a.w) * LOG2E;
    }

    float h[NST];
    #pragma unroll
    for (int n = 0; n < NST; ++n) h[n] = 0.f;
    float dsum = 0.f;

    const size_t tokbase = (size_t)b * L_SEQ + (size_t)chunk * CLEN;
    const ushort* pD = dlt + tokbase * 2048 + d;
    const ushort* pU = ub  + tokbase * 2048 + d;
    const float*  pB = dbc + tokbase * 96 + RRANK;

    float rd[2][SCHUNK], ru[2][SCHUNK], rb[2][2];

    #pragma unroll
    for (int i = 0; i < SCHUNK; ++i) {
        rd[0][i] = bf2f(pD[(size_t)i * 2048]);
        ru[0][i] = bf2f(pU[(size_t)i * 2048]);
    }
    #pragma unroll
    for (int i = 0; i < 2; ++i) {
        int e = i * 64 + lane;
        rb[0][i] = pB[(size_t)(e >> 4) * 96 + (e & 15)];
    }

    #pragma unroll
    for (int st = 0; st < NSTAGE; ++st) {
        const int cur = st & 1, nxt = cur ^ 1;
        #pragma unroll
        for (int i = 0; i < 2; ++i) {
            int e = i * 64 + lane;
            sB[wave][e >> 4][e & 15] = rb[cur][i];
        }
        if (st + 1 < NSTAGE) {
            const size_t to = (size_t)(st + 1) * SCHUNK;
            #pragma unroll
            for (int i = 0; i < SCHUNK; ++i) {
                rd[nxt][i] = bf2f(pD[(to + i) * 2048]);
                ru[nxt][i] = bf2f(pU[(to + i) * 2048]);
            }
            #pragma unroll
            for (int i = 0; i < 2; ++i) {
                int e = i * 64 + lane;
                rb[nxt][i] = pB[(to + (e >> 4)) * 96 + (e & 15)];
            }
        }
        #pragma unroll
        for (int s = 0; s < SCHUNK; ++s) {
            float delta = rd[cur][s];
            float du    = delta * ru[cur][s];
            dsum += delta;
            #pragma unroll
            for (int q = 0; q < 4; ++q) {
                float4 bq = *(const float4*)&sB[wave][s][q * 4];
                h[q*4+0] = h[q*4+0] * fexp2(delta * Al[q*4+0]) + du * bq.x;
                h[q*4+1] = h[q*4+1] * fexp2(delta * Al[q*4+1]) + du * bq.y;
                h[q*4+2] = h[q*4+2] * fexp2(delta * Al[q*4+2]) + du * bq.z;
                h[q*4+3] = h[q*4+3] * fexp2(delta * Al[q*4+3]) + du * bq.w;
            }
        }
    }

    size_t base = (((size_t)b * DIN + d) * GCHUNK + chunk) * NST;
    #pragma unroll
    for (int q = 0; q < 4; ++q)
        *(float4*)&c_out[base + q * 4] = make_float4(h[q*4], h[q*4+1], h[q*4+2], h[q*4+3]);
    dsum_out[((size_t)b * DIN + d) * GCHUNK + chunk] = dsum;
}

// ---------------------------------------------------------------------------
// Pass 2: per (b,d,n) scan the GCHUNK chunk summaries, IN PLACE over c_buf.
// ---------------------------------------------------------------------------
__global__ __launch_bounds__(256) void scan_part2(
    float* __restrict__ cbuf,
    const float* __restrict__ dsum_in,
    const float* __restrict__ A_log)
{
    int idx = blockIdx.x * 256 + threadIdx.x;
    int n   = idx & 15;
    int d   = (idx >> 4) & (DIN - 1);
    int b   = idx >> 15;

    float Al = -__expf(A_log[(size_t)d * NST + n]) * LOG2E;
    size_t cb = ((size_t)b * DIN + d) * GCHUNK;

    float h = 0.f;
    for (int ch = 0; ch < GCHUNK; ++ch) {
        size_t o = (cb + ch) * NST + n;
        float c  = cbuf[o];
        float dA = fexp2(Al * dsum_in[cb + ch]);
        cbuf[o]  = h;
        h = h * dA + c;
    }
}

// ---------------------------------------------------------------------------
// Pass 3: 4-wave blocks, WAVE-PRIVATE LDS, NO __syncthreads.  dlt BF16.
// u bf16 in (ub), z bf16 in (compact zb), y bf16 out in-place over ub.
// Grid: NBATCH * (DIN/256) * GCHUNK = 2048.
// ---------------------------------------------------------------------------
__global__ __launch_bounds__(256) void scan_part3(
    const ushort* __restrict__ dlt,     // delta bf16
    const ushort* __restrict__ zb,      // [4096][2048] bf16 (compact z)
    ushort* __restrict__ ub,            // in: u bf16, out: y bf16
    const float* __restrict__ dbc,
    const float* __restrict__ A_log,
    const float* __restrict__ Dp,
    const float* __restrict__ h_start)
{
    int chunk = blockIdx.x & (GCHUNK - 1);
    int dg    = (blockIdx.x >> 7) & 7;
    int b     = blockIdx.x >> 10;
    int wave  = threadIdx.x >> 6;
    int lane  = threadIdx.x & 63;
    int d     = dg * 256 + wave * 64 + lane;

    __shared__ float sBC[4][SCHUNK][32];   // per-wave: [s][0:16]=B, [16:32]=C

    float Al[NST];
    const float4* pA = (const float4*)(A_log + (size_t)d * NST);
    #pragma unroll
    for (int q = 0; q < 4; ++q) {
        float4 a = pA[q];
        Al[q*4+0] = -__expf(a.x) * LOG2E;
        Al[q*4+1] = -__expf(a.y) * LOG2E;
        Al[q*4+2] = -__expf(a.z) * LOG2E;
        Al[q*4+3] = -__expf(a.w) * LOG2E;
    }
    float Dd = Dp[d];

    float h[NST];
    size_t hb = (((size_t)b * DIN + d) * GCHUNK + chunk) * NST;
    #pragma unroll
    for (int q = 0; q < 4; ++q) {
        float4 v = *(const float4*)&h_start[hb + q * 4];
        h[q*4] = v.x; h[q*4+1] = v.y; h[q*4+2] = v.z; h[q*4+3] = v.w;
    }

    const size_t tokbase = (size_t)b * L_SEQ + (size_t)chunk * CLEN;
    const ushort* pD = dlt + tokbase * 2048 + d;
    const ushort* pZ = zb  + tokbase * 2048 + d;
    ushort*       pU = ub  + tokbase * 2048 + d;
    const float*  pB = dbc + tokbase * 96 + RRANK;

    float rd[2][SCHUNK], ru[2][SCHUNK], rz[2][SCHUNK], rb[2][4];

    #pragma unroll
    for (int i = 0; i < SCHUNK; ++i) {
        rd[0][i] = bf2f(pD[(size_t)i * 2048]);
        ru[0][i] = bf2f(pU[(size_t)i * 2048]);
        rz[0][i] = bf2f(pZ[(size_t)i * 2048]);
    }
    #pragma unroll
    for (int i = 0; i < 4; ++i) {
        int e = i * 64 + lane;
        rb[0][i] = pB[(size_t)(e >> 5) * 96 + (e & 31)];
    }

    #pragma unroll
    for (int st = 0; st < NSTAGE; ++st) {
        const int cur = st & 1, nxt = cur ^ 1;
        #pragma unroll
        for (int i = 0; i < 4; ++i) {
            int e = i * 64 + lane;
            sBC[wave][e >> 5][e & 31] = rb[cur][i];
        }
        if (st + 1 < NSTAGE) {
            const size_t to = (size_t)(st + 1) * SCHUNK;
            #pragma unroll
            for (int i = 0; i < SCHUNK; ++i) {
                rd[nxt][i] = bf2f(pD[(to + i) * 2048]);
                ru[nxt][i] = bf2f(pU[(to + i) * 2048]);
                rz[nxt][i] = bf2f(pZ[(to + i) * 2048]);
            }
            #pragma unroll
            for (int i = 0; i < 4; ++i) {
                int e = i * 64 + lane;
                rb[nxt][i] = pB[(to + (e >> 5)) * 96 + (e & 31)];
            }
        }
        #pragma unroll
        for (int s = 0; s < SCHUNK; ++s) {
            float delta = rd[cur][s];
            float u     = ru[cur][s];
            float du    = delta * u;
            float y = 0.f;
            #pragma unroll
            for (int q = 0; q < 4; ++q) {
                float4 bq = *(const float4*)&sBC[wave][s][q * 4];
                float4 cq = *(const float4*)&sBC[wave][s][16 + q * 4];
                h[q*4+0] = h[q*4+0] * fexp2(delta * Al[q*4+0]) + du * bq.x; y += h[q*4+0] * cq.x;
                h[q*4+1] = h[q*4+1] * fexp2(delta * Al[q*4+1]) + du * bq.y; y += h[q*4+1] * cq.y;
                h[q*4+2] = h[q*4+2] * fexp2(delta * Al[q*4+2]) + du * bq.z; y += h[q*4+2] * cq.z;
                h[q*4+3] = h[q*4+3] * fexp2(delta * Al[q*4+3]) + du * bq.w; y += h[q*4+3] * cq.w;
            }
            float z  = rz[cur][s];
            float sz = z / (1.f + __expf(-z));
            pU[((size_t)st * SCHUNK + s) * 2048] = f2bf((y + u * Dd) * sz);
        }
    }
}

// ---------------------------------------------------------------------------
// Fused split-K reduce (bf16 partials) + LayerNorm + residual.
// ---------------------------------------------------------------------------
__global__ __launch_bounds__(256) void ln4_k(
    const ushort* __restrict__ part,  // [4][4096][1024] bf16
    const float* __restrict__ x,
    const float* __restrict__ gamma, const float* __restrict__ beta,
    float* __restrict__ out)
{
    int row = blockIdx.x;
    int tid = threadIdx.x;
    const size_t off = (size_t)row * DMOD + tid * 4;

    float4 v = {0.f, 0.f, 0.f, 0.f};
    #pragma unroll
    for (int ks = 0; ks < G4_KS; ++ks) {
        ushort4 p = *(const ushort4*)(part + (size_t)ks * NTOK * DMOD + off);
        v.x += bf2f(p.x); v.y += bf2f(p.y); v.z += bf2f(p.z); v.w += bf2f(p.w);
    }

    float s  = v.x + v.y + v.z + v.w;
    float s2 = v.x * v.x + v.y * v.y + v.z * v.z + v.w * v.w;
    #pragma unroll
    for (int off2 = 32; off2 > 0; off2 >>= 1) {
        s  += __shfl_down(s, off2);
        s2 += __shfl_down(s2, off2);
    }
    __shared__ float ws[4], ws2[4];
    int wave = tid >> 6, lane = tid & 63;
    if (lane == 0) { ws[wave] = s; ws2[wave] = s2; }
    __syncthreads();
    if (tid == 0) {
        float ts = 0.f, ts2 = 0.f;
        #pragma unroll
        for (int w = 0; w < 4; ++w) { ts += ws[w]; ts2 += ws2[w]; }
        ws[0] = ts; ws2[0] = ts2;
    }
    __syncthreads();
    float mu  = ws[0] * (1.f / DMOD);
    float var = ws2[0] * (1.f / DMOD) - mu * mu;
    float rs  = rsqrtf(var + 1e-5f);

    float4 g  = ((const float4*)gamma)[tid];
    float4 be = ((const float4*)beta)[tid];
    float4 xr = *(const float4*)(x + off);
    float4 o;
    o.x = (v.x - mu) * rs * g.x + be.x + xr.x;
    o.y = (v.y - mu) * rs * g.y + be.y + xr.y;
    o.z = (v.z - mu) * rs * g.z + be.z + xr.z;
    o.w = (v.w - mu) * rs * g.w + be.w + xr.w;
    *(float4*)(out + off) = o;
}

// ---------------------------------------------------------------------------
// Workspace layout (peak 105 MB; ws_size = 256 MiB per r6 fill evidence):
//   0-16    zb | 16-32 ub | 32-48 dltb (bf16; g4part overlays 32-64 after
//   scan3) | 64-65.5 dbc | 65.5 Wdtb | 65.75 Wxb | 66.125 dtb | 67-69 dsum
//   69-73   Wob | 73-105 c_buf
//   overlays in c_buf zone (dead before scan1): xb 73-81, Wib 81-89,
//   ub_pre 89-105, g2part(bf16, 12.6 MB) 73-86
// ---------------------------------------------------------------------------
extern "C" void kernel_launch(void* const* d_in, const int* in_sizes, int n_in,
                              void* d_out, int out_size, void* d_ws, size_t ws_size,
                              hipStream_t stream)
{
    const float* x      = (const float*)d_in[0];
    const float* W_in   = (const float*)d_in[1];
    const float* w_conv = (const float*)d_in[2];
    const float* b_conv = (const float*)d_in[3];
    const float* W_x    = (const float*)d_in[4];
    const float* W_dt   = (const float*)d_in[5];
    const float* b_dt   = (const float*)d_in[6];
    const float* A_log  = (const float*)d_in[7];
    const float* Dp     = (const float*)d_in[8];
    const float* W_out  = (const float*)d_in[9];
    const float* gamma  = (const float*)d_in[10];
    const float* beta   = (const float*)d_in[11];
    float* out = (float*)d_out;

    char* ws = (char*)d_ws;
    const size_t MB = 1024 * 1024;
    ushort* zb     = (ushort*)(ws);                          // 0-16
    ushort* ub     = (ushort*)(ws + 16 * MB);                // 16-32
    ushort* dltb   = (ushort*)(ws + 32 * MB);                // 32-48 (bf16)
    float*  dbc    = (float*)(ws + 64 * MB);                 // 64-65.5
    ushort* Wdtb   = (ushort*)(ws + 65 * MB + 512 * 1024);   // 65.5-65.75
    ushort* Wxb    = (ushort*)(ws + 65 * MB + 768 * 1024);   // 65.75-66.125
    ushort* dtb    = (ushort*)(ws + 66 * MB + 128 * 1024);   // 66.125-66.625
    float*  dsum   = (float*)(ws + 67 * MB);                 // 67-69
    ushort* Wob    = (ushort*)(ws + 69 * MB);                // 69-73
    float*  c_buf  = (float*)(ws + 73 * MB);                 // 73-105
    // overlays in c_buf zone (dead before scan1):
    ushort* xb     = (ushort*)(ws + 73 * MB);                // 73-81
    ushort* Wib    = (ushort*)(ws + 81 * MB);                // 81-89
    ushort* ub_pre = (ushort*)(ws + 89 * MB);                // 89-105
    ushort* g2part = (ushort*)(ws + 73 * MB);                // 73-86 (bf16)
    // GEMM4 partials overlay dltb zone (dead after scan3):
    ushort* g4part = (ushort*)(ws + 32 * MB);                // 32-64

    dim3 blk(256);

    // 1. prep: x cast + all 4 weight transposes (8512 blocks)
    prep_k<<<dim3(8512), blk, 0, stream>>>(x, W_in, W_dt, W_x, W_out,
                                           xb, Wib, Wdtb, Wxb, Wob);
    // 2. xz = x @ W_in, split C-write: cols<2048 -> ub_pre, else -> zb
    gemm8p<<<dim3(16, 16, 1), dim3(512), 0, stream>>>(
        xb, Wib, ub_pre, 1024, 1024, 2048, 0, zb, 2048);
    // 3. u = silu(conv(u_pre)) -> bf16 ub
    conv_silu_k<<<dim3(NTOK), blk, 0, stream>>>(ub_pre, w_conv, b_conv, ub);
    // 4. dbc = u @ W_x  (MFMA split-K=16, bf16 partials + reduce w/ dt cast)
    gemm2_mfma<<<dim3(32, 1, G2_KS), blk, 0, stream>>>(ub, Wxb, g2part);
    gemm2_reduce_dt<<<dim3(NTOK * 96 / 4 / 256), blk, 0, stream>>>(g2part, dbc, dtb);
    // 5. delta = softplus(dt @ W_dt + b_dt) -> bf16 dltb (hw-softplus epilogue)
    gemm_mfma<1, 1><<<dim3(16, 32), blk, 0, stream>>>(
        dtb, Wdtb, dltb, 4096, 2048, 64, 2048, b_dt);
    // 6. chunked selective scan (GCHUNK=128, 4-wave wave-private scan blocks)
    scan_part1<<<dim3(NBATCH * 8 * GCHUNK), blk, 0, stream>>>(
        dltb, ub, dbc, A_log, c_buf, dsum);
    scan_part2<<<dim3(NBATCH * DIN * NST / 256), blk, 0, stream>>>(
        c_buf, dsum, A_log);
    scan_part3<<<dim3(NBATCH * 8 * GCHUNK), blk, 0, stream>>>(
        dltb, zb, ub, dbc, A_log, Dp, c_buf);
    // 7. out_pre partials = y @ W_out^T  (ring-2 2-blk/CU GEMM, split-K=4)
    gemm8p<<<dim3(4, 16, G4_KS), dim3(512), 0, stream>>>(
        ub, Wob, g4part, 2048, G4_KC, DMOD, (size_t)NTOK * DMOD,
        nullptr, 0x7fffffff);
    // 8. fused reduce + LayerNorm + residual
    ln4_k<<<dim3(NTOK), blk, 0, stream>>>(g4part, x, gamma, beta, out);
}

// Round 13
// 310.710 us; speedup vs baseline: 2.8010x; 2.8010x over previous
//
#include <hip/hip_runtime.h>
#include <math.h>

#define L_SEQ 2048
#define DMOD  1024
#define DIN   2048
#define NBATCH 2
#define NTOK  (NBATCH * L_SEQ)   // 4096 tokens
#define NST   16
#define RRANK 64
#define LOG2E 1.44269504088896f

#define GCHUNK 128                // chunks along L
#define CLEN   (L_SEQ / GCHUNK)   // 16 steps per chunk
#define SCHUNK 8                  // software-pipeline stage depth
#define NSTAGE (CLEN / SCHUNK)    // 2 stages per chunk

#define G4_KS   4                 // GEMM4 split-K factor
#define G4_KC   (2048 / G4_KS)    // 512 k per slice
#define G2_KS   16                // GEMM2 split-K factor
#define G2_KC   (2048 / G2_KS)    // 128 k per slice

typedef __attribute__((ext_vector_type(8))) short  short8;   // 8 bf16
typedef __attribute__((ext_vector_type(4))) float  f32x4;

__device__ __forceinline__ ushort f2bf(float f) {
    unsigned u = __float_as_uint(f);
    u += 0x7fffu + ((u >> 16) & 1u);
    return (ushort)(u >> 16);
}
__device__ __forceinline__ float bf2f(ushort u) {
    return __uint_as_float(((unsigned)u) << 16);
}
__device__ __forceinline__ float fexp2(float x) {
    return __builtin_amdgcn_exp2f(x);
}

// async global->LDS DMA, 16 B per lane; lds dest = wave-uniform base + lane*16
__device__ __forceinline__ void gload16(const ushort* g, ushort* l) {
    __builtin_amdgcn_global_load_lds(
        (const __attribute__((address_space(1))) unsigned int*)g,
        (__attribute__((address_space(3))) unsigned int*)l,
        16, 0, 0);
}

// ---------------------------------------------------------------------------
// Device helpers: flat cast (2048 elems/block) and 32x32 transpose-cast tile.
// ---------------------------------------------------------------------------
__device__ __forceinline__ void cast_body(
    const float* __restrict__ src, ushort* __restrict__ dst, int bid, int tid)
{
    int i = (bid * 256 + tid) * 8;
    float4 a = *(const float4*)(src + i);
    float4 b = *(const float4*)(src + i + 4);
    ushort4 o0 = make_ushort4(f2bf(a.x), f2bf(a.y), f2bf(a.z), f2bf(a.w));
    ushort4 o1 = make_ushort4(f2bf(b.x), f2bf(b.y), f2bf(b.z), f2bf(b.w));
    *(ushort4*)(dst + i)     = o0;
    *(ushort4*)(dst + i + 4) = o1;
}

__device__ __forceinline__ void tcast_body(
    const float* __restrict__ src, ushort* __restrict__ dst,
    int R, int C, int bx, int by, int tid)
{
    __shared__ float t[32][33];
    int tx = tid & 31;
    int ty = tid >> 5;          // 0..7
    int c0 = bx * 32;
    int r0 = by * 32;
    #pragma unroll
    for (int i = 0; i < 4; ++i)
        t[ty + i * 8][tx] = src[(size_t)(r0 + ty + i * 8) * C + c0 + tx];
    __syncthreads();
    #pragma unroll
    for (int i = 0; i < 4; ++i)
        dst[(size_t)(c0 + ty + i * 8) * R + r0 + tx] = f2bf(t[tx][ty + i * 8]);
}

// ---------------------------------------------------------------------------
// Fused prep: x cast + ALL weight transpose-casts in one launch.
// ---------------------------------------------------------------------------
__global__ __launch_bounds__(256) void prep_k(
    const float* __restrict__ x, const float* __restrict__ W_in,
    const float* __restrict__ W_dt, const float* __restrict__ W_x,
    const float* __restrict__ W_out,
    ushort* __restrict__ xb, ushort* __restrict__ Wib,
    ushort* __restrict__ Wdtb, ushort* __restrict__ Wxb,
    ushort* __restrict__ Wob)
{
    int bid = blockIdx.x, tid = threadIdx.x;
    if (bid < 2048) {
        cast_body(x, xb, bid, tid);
    } else if (bid < 6144) {
        int t = bid - 2048;                 // W_in: R=1024, C=4096
        tcast_body(W_in, Wib, 1024, 4096, t & 127, t >> 7, tid);
    } else if (bid < 6272) {
        int t = bid - 6144;                 // W_dt: R=64, C=2048
        tcast_body(W_dt, Wdtb, 64, 2048, t & 63, t >> 6, tid);
    } else if (bid < 6464) {
        int t = bid - 6272;                 // W_x: R=2048, C=96 -> [96][2048]
        tcast_body(W_x, Wxb, 2048, 96, t % 3, t / 3, tid);
    } else {
        int t = bid - 6464;                 // W_out: R=2048, C=1024
        tcast_body(W_out, Wob, 2048, 1024, t & 31, t >> 5, tid);
    }
}

// ---------------------------------------------------------------------------
// 256x256-tile 8-wave bf16 MFMA GEMM, ring-4 deep prefetch + register
// read-ahead.  (r11 version restored after r12's launch_bounds(512,4)
// register-spill catastrophe: 128-VGPR cap spilled acc[8][4] to scratch —
// FETCH 37->757 MB, 41.5->406 us.  Keep (512,2): 108 VGPR, no spill.)
// ---------------------------------------------------------------------------
__global__ __launch_bounds__(512, 2) void gemm8p(
    const ushort* __restrict__ A,    // [M][K] bf16
    const ushort* __restrict__ Bt,   // [N][K] bf16
    ushort* __restrict__ C,          // bf16, leading dim ldc
    int K, int kslice, int ldc, size_t zstride,
    ushort* __restrict__ C2, int nsplit)
{
    // [4 slots][A 8192 | B 8192] ushorts = 128 KB
    __shared__ ushort lds[65536];

    const int tid  = threadIdx.x;
    const int wave = tid >> 6;
    const int lane = tid & 63;
    const int wr   = wave >> 2;      // 0..1: wave-row (128 rows each)
    const int wc   = wave & 3;       // 0..3: wave-col (64 cols each)

    // XCD-chunked bijective swizzle (nwg % 8 == 0 for all call sites)
    const int gx = gridDim.x;
    int flat = blockIdx.y * gx + blockIdx.x;
    const int cpx = (gx * gridDim.y) >> 3;
    flat = (flat & 7) * cpx + (flat >> 3);
    const int bx = flat % gx;
    const int by = flat / gx;
    const int m0 = by * 256;
    const int n0 = bx * 256;
    const int kbeg = blockIdx.z * kslice;
    const int NH   = kslice >> 5;    // half-tiles of 32 k (even: 32 or 16)

    // --- staging source pointers (pre-swizzled global granule) ---
    const int rr  = tid >> 2;
    const int gsw = ((tid & 3) ^ ((tid >> 3) & 3)) * 8;
    const ushort* a0 = A  + (size_t)(m0 + rr)        * K + kbeg + gsw;
    const ushort* a1 = A  + (size_t)(m0 + 128 + rr)  * K + kbeg + gsw;
    const ushort* b0p = Bt + (size_t)(n0 + rr)       * K + kbeg + gsw;
    const ushort* b1p = Bt + (size_t)(n0 + 128 + rr) * K + kbeg + gsw;

    // stage one op-unit (A or B) of half-tile h_ into slot h_&3
    #define STAGE_H(op_, h_) do {                                              \
        const int ko_ = (h_) * 32;                                             \
        ushort* l_ = lds + ((h_) & 3) * 16384 + (op_) * 8192 + wave * 512;     \
        if ((op_) == 0) { gload16(a0 + ko_, l_);  gload16(a1 + ko_, l_ + 4096); }\
        else            { gload16(b0p + ko_, l_); gload16(b1p + ko_, l_ + 4096); }\
    } while (0)

    // --- fragment read offsets (same verified involution as store side) ---
    const int lr  = lane & 15;
    const int swr = ((lane >> 4) ^ ((lr >> 1) & 3)) * 8;

    #define LDAH(i_, h_) (*(const short8*)&lds[((h_) & 3) * 16384              \
        + (wr * 128 + (i_) * 16 + lr) * 32 + swr])
    #define LDBH(j_, h_) (*(const short8*)&lds[((h_) & 3) * 16384 + 8192       \
        + (wc * 64 + (j_) * 16 + lr) * 32 + swr])

    #define MFMA16(as_, bs_, off_) do {                                        \
        __builtin_amdgcn_s_setprio(1);                                         \
        _Pragma("unroll")                                                      \
        for (int i = 0; i < 4; ++i)                                            \
            _Pragma("unroll")                                                  \
            for (int j = 0; j < 4; ++j)                                        \
                acc[(off_) + i][j] = __builtin_amdgcn_mfma_f32_16x16x32_bf16(  \
                    as_[i], bs_[j], acc[(off_) + i][j], 0, 0, 0);              \
        __builtin_amdgcn_s_setprio(0);                                         \
    } while (0)

    #define VMC_B(h_) do {                                                     \
        if ((h_) + 3 < NH)                                                     \
            asm volatile("s_waitcnt vmcnt(8)" ::: "memory");                   \
        else if ((h_) + 2 < NH)                                                \
            asm volatile("s_waitcnt vmcnt(4)" ::: "memory");                   \
        else                                                                   \
            asm volatile("s_waitcnt vmcnt(0)" ::: "memory");                   \
    } while (0)

    f32x4 acc[8][4];
    #pragma unroll
    for (int i = 0; i < 8; ++i)
        #pragma unroll
        for (int j = 0; j < 4; ++j)
            acc[i][j] = (f32x4){0.f, 0.f, 0.f, 0.f};

    // prologue: stage half-tiles 0,1,2 (12 loads); retire h0 -> vmcnt(8)
    STAGE_H(0, 0); STAGE_H(1, 0);
    STAGE_H(0, 1); STAGE_H(1, 1);
    STAGE_H(0, 2); STAGE_H(1, 2);
    asm volatile("s_waitcnt vmcnt(8)" ::: "memory");
    __builtin_amdgcn_s_barrier();

    short8 aLo[4], aHi[4], bE[4], bO[4];
    // pre-read phase-0 fragments (slot 0 confirmed above)
    #pragma unroll
    for (int i = 0; i < 4; ++i) aLo[i] = LDAH(i, 0);
    #pragma unroll
    for (int j = 0; j < 4; ++j) bE[j]  = LDBH(j, 0);

    for (int hp = 0; hp < NH / 2; ++hp) {
        const int h0 = 2 * hp, h1 = 2 * hp + 1;

        // ---- A(h0): MFMA(aLo,bE); read-ahead aHi(h0) ----------------------
        if (h0 + 3 < NH) STAGE_H(0, h0 + 3);
        __builtin_amdgcn_s_barrier();
        #pragma unroll
        for (int i = 0; i < 4; ++i) aHi[i] = LDAH(4 + i, h0);
        asm volatile("s_waitcnt lgkmcnt(4)" ::: "memory");
        __builtin_amdgcn_sched_barrier(0);
        MFMA16(aLo, bE, 0);
        __builtin_amdgcn_s_barrier();

        // ---- B(h0): MFMA(aHi,bE); read-ahead aLo(h1), bO(h1) --------------
        if (h0 + 3 < NH) STAGE_H(1, h0 + 3);
        VMC_B(h0);
        __builtin_amdgcn_s_barrier();
        #pragma unroll
        for (int i = 0; i < 4; ++i) aLo[i] = LDAH(i, h1);
        #pragma unroll
        for (int j = 0; j < 4; ++j) bO[j]  = LDBH(j, h1);
        asm volatile("s_waitcnt lgkmcnt(8)" ::: "memory");
        __builtin_amdgcn_sched_barrier(0);
        MFMA16(aHi, bE, 4);
        __builtin_amdgcn_s_barrier();

        // ---- A(h1): MFMA(aLo,bO); read-ahead aHi(h1) ----------------------
        if (h1 + 3 < NH) STAGE_H(0, h1 + 3);
        __builtin_amdgcn_s_barrier();
        #pragma unroll
        for (int i = 0; i < 4; ++i) aHi[i] = LDAH(4 + i, h1);
        asm volatile("s_waitcnt lgkmcnt(4)" ::: "memory");
        __builtin_amdgcn_sched_barrier(0);
        MFMA16(aLo, bO, 0);
        __builtin_amdgcn_s_barrier();

        // ---- B(h1): MFMA(aHi,bO); read-ahead aLo(h1+1), bE(h1+1) ----------
        if (h1 + 3 < NH) STAGE_H(1, h1 + 3);
        VMC_B(h1);
        __builtin_amdgcn_s_barrier();
        if (h1 + 1 < NH) {
            #pragma unroll
            for (int i = 0; i < 4; ++i) aLo[i] = LDAH(i, h1 + 1);
            #pragma unroll
            for (int j = 0; j < 4; ++j) bE[j]  = LDBH(j, h1 + 1);
            asm volatile("s_waitcnt lgkmcnt(8)" ::: "memory");
        } else {
            asm volatile("s_waitcnt lgkmcnt(0)" ::: "memory");
        }
        __builtin_amdgcn_sched_barrier(0);
        MFMA16(aHi, bO, 4);
        __builtin_amdgcn_s_barrier();
    }
    #undef STAGE_H
    #undef LDAH
    #undef LDBH
    #undef MFMA16
    #undef VMC_B

    // C/D layout: col = lane&15, row = (lane>>4)*4 + reg  (verified mapping)
    ushort* Cp = C + (size_t)blockIdx.z * zstride;
    int ncol = n0;
    if (C2 != nullptr && n0 >= nsplit) { Cp = C2; ncol = n0 - nsplit; }
    const int rb = m0 + wr * 128 + ((lane >> 4) << 2);
    const int cb = ncol + wc * 64 + lr;
    #pragma unroll
    for (int i = 0; i < 8; ++i)
        #pragma unroll
        for (int j = 0; j < 4; ++j)
            #pragma unroll
            for (int r = 0; r < 4; ++r)
                Cp[(size_t)(rb + i * 16 + r) * ldc + cb + j * 16] =
                    f2bf(acc[i][j][r]);
}

// ---------------------------------------------------------------------------
// bf16 MFMA GEMM, BK=32 + XOR-swizzled LDS. Kept for GEMM3 (K=64).
// EPI=1: softplus(acc + bias[col]) via hw exp2/log; bias hoisted.
// OBF=1 -> bf16 output (dlt stored as bf16).
// ---------------------------------------------------------------------------
template<int EPI, int OBF>
__global__ __launch_bounds__(256) void gemm_mfma(
    const ushort* __restrict__ A,   // [M][K] bf16
    const ushort* __restrict__ Bt,  // [N][K] bf16
    void* __restrict__ Cv,          // fp32 or bf16, leading dim ldc
    int M, int N, int K, int ldc, const float* __restrict__ bias)
{
    __shared__ ushort As[128 * 32];   // 8 KB
    __shared__ ushort Bs[128 * 32];

    const int tid  = threadIdx.x;
    const int wave = tid >> 6;
    const int lane = tid & 63;
    const int wm   = (wave & 1) * 64;
    const int wn   = (wave >> 1) * 64;
    const int m0   = blockIdx.y * 128;
    const int n0   = blockIdx.x * 128;

    const int srow = lane >> 2;                       // 0..15
    const int sg   = (lane & 3) ^ ((srow >> 1) & 3);  // swizzled src granule
    const ushort* gA0 = A  + (size_t)(m0 + wave * 32 + srow)      * K + sg * 8;
    const ushort* gA1 = A  + (size_t)(m0 + wave * 32 + 16 + srow) * K + sg * 8;
    const ushort* gB0 = Bt + (size_t)(n0 + wave * 32 + srow)      * K + sg * 8;
    const ushort* gB1 = Bt + (size_t)(n0 + wave * 32 + 16 + srow) * K + sg * 8;
    ushort* lA0 = As + (wave * 32)      * 32;
    ushort* lA1 = As + (wave * 32 + 16) * 32;
    ushort* lB0 = Bs + (wave * 32)      * 32;
    ushort* lB1 = Bs + (wave * 32 + 16) * 32;

    const int lrow = lane & 15;
    const int swr  = ((lane >> 4) ^ ((lrow >> 1) & 3)) * 8;

    f32x4 acc[4][4];
    #pragma unroll
    for (int i = 0; i < 4; ++i)
        #pragma unroll
        for (int j = 0; j < 4; ++j)
            acc[i][j] = (f32x4){0.f, 0.f, 0.f, 0.f};

    for (int k0 = 0; k0 < K; k0 += 32) {
        __syncthreads();
        gload16(gA0 + k0, lA0);
        gload16(gA1 + k0, lA1);
        gload16(gB0 + k0, lB0);
        gload16(gB1 + k0, lB1);
        __syncthreads();

        short8 af[4], bfr[4];
        #pragma unroll
        for (int i = 0; i < 4; ++i) {
            af[i]  = *(const short8*)&As[(wm + i * 16 + lrow) * 32 + swr];
            bfr[i] = *(const short8*)&Bs[(wn + i * 16 + lrow) * 32 + swr];
        }
        #pragma unroll
        for (int i = 0; i < 4; ++i)
            #pragma unroll
            for (int j = 0; j < 4; ++j)
                acc[i][j] = __builtin_amdgcn_mfma_f32_16x16x32_bf16(
                    af[i], bfr[j], acc[i][j], 0, 0, 0);
    }

    // C/D layout: col = lane&15, row = (lane>>4)*4 + reg
    const int rb = m0 + wm + ((lane >> 4) << 2);
    const int cb = n0 + wn + lrow;

    float bias4[4];
    if (EPI == 1) {
        #pragma unroll
        for (int j = 0; j < 4; ++j) bias4[j] = bias[cb + j * 16];
    }

    #pragma unroll
    for (int i = 0; i < 4; ++i)
        #pragma unroll
        for (int j = 0; j < 4; ++j)
            #pragma unroll
            for (int r = 0; r < 4; ++r) {
                float v = acc[i][j][r];
                int col = cb + j * 16;
                if (EPI == 1) {
                    v += bias4[j];
                    if (v <= 20.f) {
                        float t = fexp2(v * LOG2E);
                        v = __builtin_amdgcn_logf(1.f + t) * (1.f / LOG2E);
                    }
                }
                size_t off = (size_t)(rb + i * 16 + r) * ldc + col;
                if (OBF) ((ushort*)Cv)[off] = f2bf(v);
                else     ((float*)Cv)[off]  = v;
            }
}

// ---------------------------------------------------------------------------
// GEMM2 MFMA split-K: part[ks] (bf16) = ub @ Wxb^T over 128-k slice.
// ---------------------------------------------------------------------------
__global__ __launch_bounds__(256) void gemm2_mfma(
    const ushort* __restrict__ A,   // [4096][2048] bf16 = ub
    const ushort* __restrict__ Bt,  // [96][2048] bf16 = Wxb
    ushort* __restrict__ part)      // [16][4096][96] bf16
{
    __shared__ ushort As[128 * 32];
    __shared__ ushort Bs[128 * 32];

    const int K = 2048;
    const int tid  = threadIdx.x;
    const int wave = tid >> 6;
    const int lane = tid & 63;
    const int wm   = (wave & 1) * 64;
    const int wn   = (wave >> 1) * 64;
    const int m0   = blockIdx.x * 128;
    const int ks   = blockIdx.z;

    const int srow = lane >> 2;
    const int sg   = (lane & 3) ^ ((srow >> 1) & 3);
    int rB0 = wave * 32 + srow;      if (rB0 > 95) rB0 = 95;
    int rB1 = wave * 32 + 16 + srow; if (rB1 > 95) rB1 = 95;
    const ushort* gA0 = A  + (size_t)(m0 + wave * 32 + srow)      * K + sg * 8;
    const ushort* gA1 = A  + (size_t)(m0 + wave * 32 + 16 + srow) * K + sg * 8;
    const ushort* gB0 = Bt + (size_t)rB0 * K + sg * 8;
    const ushort* gB1 = Bt + (size_t)rB1 * K + sg * 8;
    ushort* lA0 = As + (wave * 32)      * 32;
    ushort* lA1 = As + (wave * 32 + 16) * 32;
    ushort* lB0 = Bs + (wave * 32)      * 32;
    ushort* lB1 = Bs + (wave * 32 + 16) * 32;

    const int lrow = lane & 15;
    const int swr  = ((lane >> 4) ^ ((lrow >> 1) & 3)) * 8;

    f32x4 acc[4][4];
    #pragma unroll
    for (int i = 0; i < 4; ++i)
        #pragma unroll
        for (int j = 0; j < 4; ++j)
            acc[i][j] = (f32x4){0.f, 0.f, 0.f, 0.f};

    const int kbeg = ks * G2_KC, kend = kbeg + G2_KC;
    for (int k0 = kbeg; k0 < kend; k0 += 32) {
        __syncthreads();
        gload16(gA0 + k0, lA0);
        gload16(gA1 + k0, lA1);
        gload16(gB0 + k0, lB0);
        gload16(gB1 + k0, lB1);
        __syncthreads();

        short8 af[4], bfr[4];
        #pragma unroll
        for (int i = 0; i < 4; ++i) {
            af[i]  = *(const short8*)&As[(wm + i * 16 + lrow) * 32 + swr];
            bfr[i] = *(const short8*)&Bs[(wn + i * 16 + lrow) * 32 + swr];
        }
        #pragma unroll
        for (int i = 0; i < 4; ++i)
            #pragma unroll
            for (int j = 0; j < 4; ++j)
                acc[i][j] = __builtin_amdgcn_mfma_f32_16x16x32_bf16(
                    af[i], bfr[j], acc[i][j], 0, 0, 0);
    }

    ushort* po = part + (size_t)ks * NTOK * 96;
    const int rb = m0 + wm + ((lane >> 4) << 2);
    const int cb = wn + lrow;
    #pragma unroll
    for (int i = 0; i < 4; ++i)
        #pragma unroll
        for (int j = 0; j < 4; ++j) {
            int col = cb + j * 16;
            if (col < 96) {
                #pragma unroll
                for (int r = 0; r < 4; ++r)
                    po[(size_t)(rb + i * 16 + r) * 96 + col] = f2bf(acc[i][j][r]);
            }
        }
}

// ---------------------------------------------------------------------------
// GEMM2 reduce (16 bf16 slices) + fused dt bf16 cast (cols 0:64 -> dtb).
// ---------------------------------------------------------------------------
__global__ __launch_bounds__(256) void gemm2_reduce_dt(
    const ushort* __restrict__ part, float* __restrict__ dbc,
    ushort* __restrict__ dtb)
{
    int i = (blockIdx.x * 256 + threadIdx.x) * 4;
    float4 s = {0.f, 0.f, 0.f, 0.f};
    #pragma unroll
    for (int ks = 0; ks < G2_KS; ++ks) {
        ushort4 v = *(const ushort4*)(part + (size_t)ks * NTOK * 96 + i);
        s.x += bf2f(v.x); s.y += bf2f(v.y); s.z += bf2f(v.z); s.w += bf2f(v.w);
    }
    *(float4*)(dbc + i) = s;
    int col = i % 96;
    if (col < RRANK) {
        int row = i / 96;
        ushort* q = dtb + (size_t)row * RRANK + col;
        q[0] = f2bf(s.x); q[1] = f2bf(s.y); q[2] = f2bf(s.z); q[3] = f2bf(s.w);
    }
}

// ---------------------------------------------------------------------------
// Causal depthwise conv (K=4) + SiLU.  Reads COMPACT u buffer [4096][2048].
// ---------------------------------------------------------------------------
__global__ __launch_bounds__(256) void conv_silu_k(
    const ushort* __restrict__ up, const float* __restrict__ w_conv,
    const float* __restrict__ b_conv, ushort* __restrict__ ub)
{
    const int token = blockIdx.x;          // 0..4095
    const int d     = threadIdx.x * 8;     // 0..2040
    const int t     = token & (L_SEQ - 1);

    float4 w[8];
    const float4* pw = (const float4*)(w_conv + (size_t)d * 4);
    #pragma unroll
    for (int i = 0; i < 8; ++i) w[i] = pw[i];

    float acc[8];
    {
        float4 bc0 = *(const float4*)(b_conv + d);
        float4 bc1 = *(const float4*)(b_conv + d + 4);
        acc[0] = bc0.x; acc[1] = bc0.y; acc[2] = bc0.z; acc[3] = bc0.w;
        acc[4] = bc1.x; acc[5] = bc1.y; acc[6] = bc1.z; acc[7] = bc1.w;
    }

    #pragma unroll
    for (int k = 0; k < 4; ++k) {
        int tt = t - 3 + k;
        if (tt >= 0) {
            short8 v = *(const short8*)(up + (size_t)(token - 3 + k) * 2048 + d);
            #pragma unroll
            for (int i = 0; i < 8; ++i)
                acc[i] += bf2f((ushort)v[i]) * (&w[i].x)[k];
        }
    }

    short8 o;
    #pragma unroll
    for (int i = 0; i < 8; ++i) {
        float s = acc[i] / (1.f + __expf(-acc[i]));
        o[i] = (short)f2bf(s);
    }
    *(short8*)(ub + (size_t)token * DIN + d) = o;
}

// ---------------------------------------------------------------------------
// Scan pass 1: 4-wave blocks, WAVE-PRIVATE LDS (no cross-wave sharing, NO
// __syncthreads).  dlt BF16.  Grid: NBATCH * (DIN/256) * GCHUNK = 2048.
// ---------------------------------------------------------------------------
__global__ __launch_bounds__(256) void scan_part1(
    const ushort* __restrict__ dlt,    // [4096][2048] bf16
    const ushort* __restrict__ ub,     // [4096][2048] bf16
    const float* __restrict__ dbc,
    const float* __restrict__ A_log,
    float* __restrict__ c_out,         // [2][2048][GCHUNK][16]
    float* __restrict__ dsum_out)      // [2][2048][GCHUNK]
{
    int chunk = blockIdx.x & (GCHUNK - 1);
    int dg    = (blockIdx.x >> 7) & 7;
    int b     = blockIdx.x >> 10;
    int wave  = threadIdx.x >> 6;
    int lane  = threadIdx.x & 63;
    int d     = dg * 256 + wave * 64 + lane;

    __shared__ float sB[4][SCHUNK][16];   // per-wave private slice

    float Al[NST];
    const float4* pA = (const float4*)(A_log + (size_t)d * NST);
    #pragma unroll
    for (int q = 0; q < 4; ++q) {
        float4 a = pA[q];
        Al[q*4+0] = -__expf(a.x) * LOG2E;
        Al[q*4+1] = -__expf(a.y) * LOG2E;
        Al[q*4+2] = -__expf(a.z) * LOG2E;
        Al[q*4+3] = -__expf(a.w) * LOG2E;
    }

    float h[NST];
    #pragma unroll
    for (int n = 0; n < NST; ++n) h[n] = 0.f;
    float dsum = 0.f;

    const size_t tokbase = (size_t)b * L_SEQ + (size_t)chunk * CLEN;
    const ushort* pD = dlt + tokbase * 2048 + d;
    const ushort* pU = ub  + tokbase * 2048 + d;
    const float*  pB = dbc + tokbase * 96 + RRANK;

    float rd[2][SCHUNK], ru[2][SCHUNK], rb[2][2];

    #pragma unroll
    for (int i = 0; i < SCHUNK; ++i) {
        rd[0][i] = bf2f(pD[(size_t)i * 2048]);
        ru[0][i] = bf2f(pU[(size_t)i * 2048]);
    }
    #pragma unroll
    for (int i = 0; i < 2; ++i) {
        int e = i * 64 + lane;
        rb[0][i] = pB[(size_t)(e >> 4) * 96 + (e & 15)];
    }

    #pragma unroll
    for (int st = 0; st < NSTAGE; ++st) {
        const int cur = st & 1, nxt = cur ^ 1;
        #pragma unroll
        for (int i = 0; i < 2; ++i) {
            int e = i * 64 + lane;
            sB[wave][e >> 4][e & 15] = rb[cur][i];
        }
        if (st + 1 < NSTAGE) {
            const size_t to = (size_t)(st + 1) * SCHUNK;
            #pragma unroll
            for (int i = 0; i < SCHUNK; ++i) {
                rd[nxt][i] = bf2f(pD[(to + i) * 2048]);
                ru[nxt][i] = bf2f(pU[(to + i) * 2048]);
            }
            #pragma unroll
            for (int i = 0; i < 2; ++i) {
                int e = i * 64 + lane;
                rb[nxt][i] = pB[(to + (e >> 4)) * 96 + (e & 15)];
            }
        }
        #pragma unroll
        for (int s = 0; s < SCHUNK; ++s) {
            float delta = rd[cur][s];
            float du    = delta * ru[cur][s];
            dsum += delta;
            #pragma unroll
            for (int q = 0; q < 4; ++q) {
                float4 bq = *(const float4*)&sB[wave][s][q * 4];
                h[q*4+0] = h[q*4+0] * fexp2(delta * Al[q*4+0]) + du * bq.x;
                h[q*4+1] = h[q*4+1] * fexp2(delta * Al[q*4+1]) + du * bq.y;
                h[q*4+2] = h[q*4+2] * fexp2(delta * Al[q*4+2]) + du * bq.z;
                h[q*4+3] = h[q*4+3] * fexp2(delta * Al[q*4+3]) + du * bq.w;
            }
        }
    }

    size_t base = (((size_t)b * DIN + d) * GCHUNK + chunk) * NST;
    #pragma unroll
    for (int q = 0; q < 4; ++q)
        *(float4*)&c_out[base + q * 4] = make_float4(h[q*4], h[q*4+1], h[q*4+2], h[q*4+3]);
    dsum_out[((size_t)b * DIN + d) * GCHUNK + chunk] = dsum;
}

// ---------------------------------------------------------------------------
// Pass 2: per (b,d,n) scan the GCHUNK chunk summaries, IN PLACE over c_buf.
// ---------------------------------------------------------------------------
__global__ __launch_bounds__(256) void scan_part2(
    float* __restrict__ cbuf,
    const float* __restrict__ dsum_in,
    const float* __restrict__ A_log)
{
    int idx = blockIdx.x * 256 + threadIdx.x;
    int n   = idx & 15;
    int d   = (idx >> 4) & (DIN - 1);
    int b   = idx >> 15;

    float Al = -__expf(A_log[(size_t)d * NST + n]) * LOG2E;
    size_t cb = ((size_t)b * DIN + d) * GCHUNK;

    float h = 0.f;
    for (int ch = 0; ch < GCHUNK; ++ch) {
        size_t o = (cb + ch) * NST + n;
        float c  = cbuf[o];
        float dA = fexp2(Al * dsum_in[cb + ch]);
        cbuf[o]  = h;
        h = h * dA + c;
    }
}

// ---------------------------------------------------------------------------
// Pass 3: 4-wave blocks, WAVE-PRIVATE LDS, NO __syncthreads.  dlt BF16.
// u bf16 in (ub), z bf16 in (compact zb), y bf16 out in-place over ub.
// Grid: NBATCH * (DIN/256) * GCHUNK = 2048.
// ---------------------------------------------------------------------------
__global__ __launch_bounds__(256) void scan_part3(
    const ushort* __restrict__ dlt,     // delta bf16
    const ushort* __restrict__ zb,      // [4096][2048] bf16 (compact z)
    ushort* __restrict__ ub,            // in: u bf16, out: y bf16
    const float* __restrict__ dbc,
    const float* __restrict__ A_log,
    const float* __restrict__ Dp,
    const float* __restrict__ h_start)
{
    int chunk = blockIdx.x & (GCHUNK - 1);
    int dg    = (blockIdx.x >> 7) & 7;
    int b     = blockIdx.x >> 10;
    int wave  = threadIdx.x >> 6;
    int lane  = threadIdx.x & 63;
    int d     = dg * 256 + wave * 64 + lane;

    __shared__ float sBC[4][SCHUNK][32];   // per-wave: [s][0:16]=B, [16:32]=C

    float Al[NST];
    const float4* pA = (const float4*)(A_log + (size_t)d * NST);
    #pragma unroll
    for (int q = 0; q < 4; ++q) {
        float4 a = pA[q];
        Al[q*4+0] = -__expf(a.x) * LOG2E;
        Al[q*4+1] = -__expf(a.y) * LOG2E;
        Al[q*4+2] = -__expf(a.z) * LOG2E;
        Al[q*4+3] = -__expf(a.w) * LOG2E;
    }
    float Dd = Dp[d];

    float h[NST];
    size_t hb = (((size_t)b * DIN + d) * GCHUNK + chunk) * NST;
    #pragma unroll
    for (int q = 0; q < 4; ++q) {
        float4 v = *(const float4*)&h_start[hb + q * 4];
        h[q*4] = v.x; h[q*4+1] = v.y; h[q*4+2] = v.z; h[q*4+3] = v.w;
    }

    const size_t tokbase = (size_t)b * L_SEQ + (size_t)chunk * CLEN;
    const ushort* pD = dlt + tokbase * 2048 + d;
    const ushort* pZ = zb  + tokbase * 2048 + d;
    ushort*       pU = ub  + tokbase * 2048 + d;
    const float*  pB = dbc + tokbase * 96 + RRANK;

    float rd[2][SCHUNK], ru[2][SCHUNK], rz[2][SCHUNK], rb[2][4];

    #pragma unroll
    for (int i = 0; i < SCHUNK; ++i) {
        rd[0][i] = bf2f(pD[(size_t)i * 2048]);
        ru[0][i] = bf2f(pU[(size_t)i * 2048]);
        rz[0][i] = bf2f(pZ[(size_t)i * 2048]);
    }
    #pragma unroll
    for (int i = 0; i < 4; ++i) {
        int e = i * 64 + lane;
        rb[0][i] = pB[(size_t)(e >> 5) * 96 + (e & 31)];
    }

    #pragma unroll
    for (int st = 0; st < NSTAGE; ++st) {
        const int cur = st & 1, nxt = cur ^ 1;
        #pragma unroll
        for (int i = 0; i < 4; ++i) {
            int e = i * 64 + lane;
            sBC[wave][e >> 5][e & 31] = rb[cur][i];
        }
        if (st + 1 < NSTAGE) {
            const size_t to = (size_t)(st + 1) * SCHUNK;
            #pragma unroll
            for (int i = 0; i < SCHUNK; ++i) {
                rd[nxt][i] = bf2f(pD[(to + i) * 2048]);
                ru[nxt][i] = bf2f(pU[(to + i) * 2048]);
                rz[nxt][i] = bf2f(pZ[(to + i) * 2048]);
            }
            #pragma unroll
            for (int i = 0; i < 4; ++i) {
                int e = i * 64 + lane;
                rb[nxt][i] = pB[(to + (e >> 5)) * 96 + (e & 31)];
            }
        }
        #pragma unroll
        for (int s = 0; s < SCHUNK; ++s) {
            float delta = rd[cur][s];
            float u     = ru[cur][s];
            float du    = delta * u;
            float y = 0.f;
            #pragma unroll
            for (int q = 0; q < 4; ++q) {
                float4 bq = *(const float4*)&sBC[wave][s][q * 4];
                float4 cq = *(const float4*)&sBC[wave][s][16 + q * 4];
                h[q*4+0] = h[q*4+0] * fexp2(delta * Al[q*4+0]) + du * bq.x; y += h[q*4+0] * cq.x;
                h[q*4+1] = h[q*4+1] * fexp2(delta * Al[q*4+1]) + du * bq.y; y += h[q*4+1] * cq.y;
                h[q*4+2] = h[q*4+2] * fexp2(delta * Al[q*4+2]) + du * bq.z; y += h[q*4+2] * cq.z;
                h[q*4+3] = h[q*4+3] * fexp2(delta * Al[q*4+3]) + du * bq.w; y += h[q*4+3] * cq.w;
            }
            float z  = rz[cur][s];
            float sz = z / (1.f + __expf(-z));
            pU[((size_t)st * SCHUNK + s) * 2048] = f2bf((y + u * Dd) * sz);
        }
    }
}

// ---------------------------------------------------------------------------
// Fused split-K reduce (bf16 partials) + LayerNorm + residual.
// ---------------------------------------------------------------------------
__global__ __launch_bounds__(256) void ln4_k(
    const ushort* __restrict__ part,  // [4][4096][1024] bf16
    const float* __restrict__ x,
    const float* __restrict__ gamma, const float* __restrict__ beta,
    float* __restrict__ out)
{
    int row = blockIdx.x;
    int tid = threadIdx.x;
    const size_t off = (size_t)row * DMOD + tid * 4;

    float4 v = {0.f, 0.f, 0.f, 0.f};
    #pragma unroll
    for (int ks = 0; ks < G4_KS; ++ks) {
        ushort4 p = *(const ushort4*)(part + (size_t)ks * NTOK * DMOD + off);
        v.x += bf2f(p.x); v.y += bf2f(p.y); v.z += bf2f(p.z); v.w += bf2f(p.w);
    }

    float s  = v.x + v.y + v.z + v.w;
    float s2 = v.x * v.x + v.y * v.y + v.z * v.z + v.w * v.w;
    #pragma unroll
    for (int off2 = 32; off2 > 0; off2 >>= 1) {
        s  += __shfl_down(s, off2);
        s2 += __shfl_down(s2, off2);
    }
    __shared__ float ws[4], ws2[4];
    int wave = tid >> 6, lane = tid & 63;
    if (lane == 0) { ws[wave] = s; ws2[wave] = s2; }
    __syncthreads();
    if (tid == 0) {
        float ts = 0.f, ts2 = 0.f;
        #pragma unroll
        for (int w = 0; w < 4; ++w) { ts += ws[w]; ts2 += ws2[w]; }
        ws[0] = ts; ws2[0] = ts2;
    }
    __syncthreads();
    float mu  = ws[0] * (1.f / DMOD);
    float var = ws2[0] * (1.f / DMOD) - mu * mu;
    float rs  = rsqrtf(var + 1e-5f);

    float4 g  = ((const float4*)gamma)[tid];
    float4 be = ((const float4*)beta)[tid];
    float4 xr = *(const float4*)(x + off);
    float4 o;
    o.x = (v.x - mu) * rs * g.x + be.x + xr.x;
    o.y = (v.y - mu) * rs * g.y + be.y + xr.y;
    o.z = (v.z - mu) * rs * g.z + be.z + xr.z;
    o.w = (v.w - mu) * rs * g.w + be.w + xr.w;
    *(float4*)(out + off) = o;
}

// ---------------------------------------------------------------------------
// Workspace layout (peak 105 MB; ws_size = 256 MiB per r6 fill evidence):
//   0-16    zb | 16-32 ub | 32-48 dltb (bf16; g4part overlays 32-64 after
//   scan3) | 64-65.5 dbc | 65.5 Wdtb | 65.75 Wxb | 66.125 dtb | 67-69 dsum
//   69-73   Wob | 73-105 c_buf
//   overlays in c_buf zone (dead before scan1): xb 73-81, Wib 81-89,
//   ub_pre 89-105, g2part(bf16, 12.6 MB) 73-86
// ---------------------------------------------------------------------------
extern "C" void kernel_launch(void* const* d_in, const int* in_sizes, int n_in,
                              void* d_out, int out_size, void* d_ws, size_t ws_size,
                              hipStream_t stream)
{
    const float* x      = (const float*)d_in[0];
    const float* W_in   = (const float*)d_in[1];
    const float* w_conv = (const float*)d_in[2];
    const float* b_conv = (const float*)d_in[3];
    const float* W_x    = (const float*)d_in[4];
    const float* W_dt   = (const float*)d_in[5];
    const float* b_dt   = (const float*)d_in[6];
    const float* A_log  = (const float*)d_in[7];
    const float* Dp     = (const float*)d_in[8];
    const float* W_out  = (const float*)d_in[9];
    const float* gamma  = (const float*)d_in[10];
    const float* beta   = (const float*)d_in[11];
    float* out = (float*)d_out;

    char* ws = (char*)d_ws;
    const size_t MB = 1024 * 1024;
    ushort* zb     = (ushort*)(ws);                          // 0-16
    ushort* ub     = (ushort*)(ws + 16 * MB);                // 16-32
    ushort* dltb   = (ushort*)(ws + 32 * MB);                // 32-48 (bf16)
    float*  dbc    = (float*)(ws + 64 * MB);                 // 64-65.5
    ushort* Wdtb   = (ushort*)(ws + 65 * MB + 512 * 1024);   // 65.5-65.75
    ushort* Wxb    = (ushort*)(ws + 65 * MB + 768 * 1024);   // 65.75-66.125
    ushort* dtb    = (ushort*)(ws + 66 * MB + 128 * 1024);   // 66.125-66.625
    float*  dsum   = (float*)(ws + 67 * MB);                 // 67-69
    ushort* Wob    = (ushort*)(ws + 69 * MB);                // 69-73
    float*  c_buf  = (float*)(ws + 73 * MB);                 // 73-105
    // overlays in c_buf zone (dead before scan1):
    ushort* xb     = (ushort*)(ws + 73 * MB);                // 73-81
    ushort* Wib    = (ushort*)(ws + 81 * MB);                // 81-89
    ushort* ub_pre = (ushort*)(ws + 89 * MB);                // 89-105
    ushort* g2part = (ushort*)(ws + 73 * MB);                // 73-86 (bf16)
    // GEMM4 partials overlay dltb zone (dead after scan3):
    ushort* g4part = (ushort*)(ws + 32 * MB);                // 32-64

    dim3 blk(256);

    // 1. prep: x cast + all 4 weight transposes (8512 blocks)
    prep_k<<<dim3(8512), blk, 0, stream>>>(x, W_in, W_dt, W_x, W_out,
                                           xb, Wib, Wdtb, Wxb, Wob);
    // 2. xz = x @ W_in, split C-write: cols<2048 -> ub_pre, else -> zb
    gemm8p<<<dim3(16, 16, 1), dim3(512), 0, stream>>>(
        xb, Wib, ub_pre, 1024, 1024, 2048, 0, zb, 2048);
    // 3. u = silu(conv(u_pre)) -> bf16 ub
    conv_silu_k<<<dim3(NTOK), blk, 0, stream>>>(ub_pre, w_conv, b_conv, ub);
    // 4. dbc = u @ W_x  (MFMA split-K=16, bf16 partials + reduce w/ dt cast)
    gemm2_mfma<<<dim3(32, 1, G2_KS), blk, 0, stream>>>(ub, Wxb, g2part);
    gemm2_reduce_dt<<<dim3(NTOK * 96 / 4 / 256), blk, 0, stream>>>(g2part, dbc, dtb);
    // 5. delta = softplus(dt @ W_dt + b_dt) -> bf16 dltb (hw-softplus epilogue)
    gemm_mfma<1, 1><<<dim3(16, 32), blk, 0, stream>>>(
        dtb, Wdtb, dltb, 4096, 2048, 64, 2048, b_dt);
    // 6. chunked selective scan (GCHUNK=128, 4-wave wave-private scan blocks)
    scan_part1<<<dim3(NBATCH * 8 * GCHUNK), blk, 0, stream>>>(
        dltb, ub, dbc, A_log, c_buf, dsum);
    scan_part2<<<dim3(NBATCH * DIN * NST / 256), blk, 0, stream>>>(
        c_buf, dsum, A_log);
    scan_part3<<<dim3(NBATCH * 8 * GCHUNK), blk, 0, stream>>>(
        dltb, zb, ub, dbc, A_log, Dp, c_buf);
    // 7. out_pre partials = y @ W_out^T  (ring-4 read-ahead GEMM, split-K=4)
    gemm8p<<<dim3(4, 16, G4_KS), dim3(512), 0, stream>>>(
        ub, Wob, g4part, 2048, G4_KC, DMOD, (size_t)NTOK * DMOD,
        nullptr, 0x7fffffff);
    // 8. fused reduce + LayerNorm + residual
    ln4_k<<<dim3(NTOK), blk, 0, stream>>>(g4part, x, gamma, beta, out);
}